// Round 2
// baseline (886.985 us; speedup 1.0000x reference)
//
#include <hip/hip_runtime.h>
#include <math.h>

// DeepGCN layer, round 11: round-10 structure with the spill cliff fixed.
//   Round-10 post-mortem: __launch_bounds__(256,8) forced VGPR=32 -> massive
//   scratch spill (FETCH 929MB / WRITE 907MB, k_ffn 650us). The LDS rework
//   itself was good (17408 B, occupancy 81%).
//   Fix: __launch_bounds__(256,6) -> VGPR cap ~85, natural alloc ~64-80,
//   no spill; occupancy set by actual VGPR count (6-7 blocks/CU vs round-0's 4).
// MFMA 16x16x32 f16 layouts (m89/m101):
//   A[m = lane&15][k = (lane>>4)*8 + j]   (half8)
//   B[k = (lane>>4)*8 + j][n = lane&15]
//   D[m = (lane>>4)*4 + r][n = lane&15]   (float4)
// N = 100000 (multiple of 32), E = 1000000. NB <= 2048.

typedef _Float16 half8  __attribute__((ext_vector_type(8)));
typedef _Float16 half2v __attribute__((ext_vector_type(2)));
typedef __fp16   fp16x2 __attribute__((ext_vector_type(2)));
typedef float    floatx4 __attribute__((ext_vector_type(4)));

#define SBLK 128   // hist/scatter edge-chunks

__device__ __forceinline__ float gelu_f(float x){
  float x2 = x*x;
  float z  = x*(1.5957691216f + 0.07135481283f*x2);
  float e  = __expf(-z);
  return x * __builtin_amdgcn_rcpf(1.0f + e);
}
__device__ __forceinline__ unsigned pk16(float a, float b){
  fp16x2 h = __builtin_amdgcn_cvt_pkrtz(a, b);
  return __builtin_bit_cast(unsigned, h);
}
__device__ __forceinline__ float wave_reduce_sum(float v){
  #pragma unroll
  for (int off = 32; off > 0; off >>= 1) v += __shfl_xor(v, off, 64);
  return v;
}

// ---------------- two-level counting sort ----------------
__global__ __launch_bounds__(256) void k_hist(const int* __restrict__ ei, int* __restrict__ cnt,
                                              int E, int NB, int ESB){
  __shared__ int h[2048];
  int t = threadIdx.x;
  for (int i = t; i < NB; i += 256) h[i] = 0;
  __syncthreads();
  int e0 = blockIdx.x * ESB;
  int e1 = min(E, e0 + ESB);
  for (int e = e0 + t; e < e1; e += 256)
    atomicAdd(&h[ei[E + e] >> 6], 1);
  __syncthreads();
  for (int i = t; i < NB; i += 256) cnt[(size_t)blockIdx.x * NB + i] = h[i];
}

// block b: exclusive scan of cnt[0..SBLK)[b]; total -> total[b]
__global__ __launch_bounds__(128) void k_scanB(int* __restrict__ cnt, int* __restrict__ total,
                                               int NB){
  __shared__ int w0sum;
  int b = blockIdx.x;
  int t = threadIdx.x, l = t & 63, w = t >> 6;
  int v = cnt[(size_t)t*NB + b];
  int x = v;
  #pragma unroll
  for (int off = 1; off < 64; off <<= 1){
    int y = __shfl_up(x, off);
    if (l >= off) x += y;
  }
  if (w == 0 && l == 63) w0sum = x;
  __syncthreads();
  int ex = x - v + (w ? w0sum : 0);
  cnt[(size_t)t*NB + b] = ex;
  if (t == 127) total[b] = ex + v;
}

// single-block scan of totals -> bucketStart[NB+1]
__global__ __launch_bounds__(256) void k_scan2(const int* __restrict__ total,
                                               int* __restrict__ bucketStart, int NB){
  __shared__ int wsum[4];
  int t = threadIdx.x, w = t >> 6, l = t & 63;
  int vals[8];
  int sum = 0;
  #pragma unroll
  for (int j = 0; j < 8; j++){
    int idx = t*8 + j;
    vals[j] = (idx < NB) ? total[idx] : 0;
    sum += vals[j];
  }
  int x = sum;
  #pragma unroll
  for (int off = 1; off < 64; off <<= 1){
    int y = __shfl_up(x, off);
    if (l >= off) x += y;
  }
  if (l == 63) wsum[w] = x;
  __syncthreads();
  if (t == 0){
    int s = 0;
    #pragma unroll
    for (int i = 0; i < 4; i++){ int c = wsum[i]; wsum[i] = s; s += c; }
  }
  __syncthreads();
  int run = wsum[w] + x - sum;
  #pragma unroll
  for (int j = 0; j < 8; j++){
    int idx = t*8 + j;
    if (idx < NB) bucketStart[idx] = run;
    run += vals[j];
  }
  if (t == 255) bucketStart[NB] = run;   // == E
}

__global__ __launch_bounds__(256) void k_scatter(const int* __restrict__ ei,
    const int* __restrict__ cnt, const int* __restrict__ bucketStart,
    int* __restrict__ eb, int E, int NB, int ESB){
  __shared__ int cur[2048];
  int t = threadIdx.x;
  for (int i = t; i < NB; i += 256)
    cur[i] = bucketStart[i] + cnt[(size_t)blockIdx.x*NB + i];
  __syncthreads();
  int e0 = blockIdx.x*ESB, e1 = min(E, e0 + ESB);
  for (int e = e0 + t; e < e1; e += 256){
    int s = ei[e], d = ei[E + e];
    int pos = atomicAdd(&cur[d >> 6], 1);
    eb[pos] = (s << 6) | (d & 63);
  }
}

// per-bucket: sort by dst&63 -> eSrc; row_start/incount/dinv
__global__ __launch_bounds__(256) void k_sort2(const int* __restrict__ eb,
    const int* __restrict__ bucketStart, int* __restrict__ eSrc,
    int* __restrict__ row_start, int* __restrict__ incount,
    float* __restrict__ dinv, int N){
  __shared__ int hcnt[64];
  __shared__ int hcur[64];
  int b = blockIdx.x, t = threadIdx.x;
  if (t < 64) hcnt[t] = 0;
  __syncthreads();
  int s0 = bucketStart[b], s1 = bucketStart[b+1];
  for (int e = s0 + t; e < s1; e += 256) atomicAdd(&hcnt[eb[e] & 63], 1);
  __syncthreads();
  if (t < 64){
    int v = hcnt[t];
    int x = v;
    #pragma unroll
    for (int off = 1; off < 64; off <<= 1){
      int y = __shfl_up(x, off);
      if (t >= off) x += y;
    }
    int ex = x - v;
    hcur[t] = ex;
    int node = (b << 6) + t;
    if (node < N){
      row_start[node] = s0 + ex;
      incount[node]   = v;
      dinv[node]      = rsqrtf((float)v + 1.0f);
    }
  }
  __syncthreads();
  for (int e = s0 + t; e < s1; e += 256){
    int v = eb[e];
    int pos = atomicAdd(&hcur[v & 63], 1);
    eSrc[s0 + pos] = v >> 6;
  }
}

// ---------------- k_prep: weight pack (blocks 0..71) + scaled LN1/gelu ----------------
__global__ __launch_bounds__(256) void k_prep(
    const float* __restrict__ Wc, const float* __restrict__ W1, const float* __restrict__ W2,
    _Float16* __restrict__ Wcp, _Float16* __restrict__ W1p, _Float16* __restrict__ W2p,
    const float* __restrict__ nf, const float* __restrict__ g, const float* __restrict__ b,
    const float* __restrict__ dinv, _Float16* __restrict__ hs)
{
  int bid = blockIdx.x;
  if (bid < 72){
    int id = bid*256 + threadIdx.x;   // 18432 total
    const float* W; _Float16* P; int K, Nc, base;
    if (id < 2048)            { W = Wc; P = Wcp; K = 128; Nc = 128; base = id; }
    else if (id < 2048+8192)  { W = W1; P = W1p; K = 128; Nc = 512; base = id - 2048; }
    else                      { W = W2; P = W2p; K = 512; Nc = 128; base = id - 10240; }
    int lane = base & 63;
    int nkb  = K >> 5;
    int kb   = (base >> 6) % nkb;
    int tile = base / (nkb << 6);
    int col  = (tile << 4) + (lane & 15);
    int k0   = (kb << 5) + ((lane >> 4) << 3);
    _Float16 v[8];
    #pragma unroll
    for (int j = 0; j < 8; j++) v[j] = (_Float16)W[(size_t)(k0 + j)*Nc + col];
    *(half8*)&P[(size_t)base * 8] = *(const half8*)v;
  } else {
    int w = threadIdx.x >> 6, l = threadIdx.x & 63;
    int node = (bid - 72)*4 + w;
    float2 x = *(const float2*)&nf[(size_t)node*128 + 2*l];
    float mu = wave_reduce_sum(x.x + x.y) * 0.0078125f;
    float d0 = x.x - mu, d1 = x.y - mu;
    float var = wave_reduce_sum(d0*d0 + d1*d1) * 0.0078125f;
    float rs = rsqrtf(var + 1e-5f);
    float dn = dinv[node];
    float y0 = dn * gelu_f(d0*rs*g[2*l]   + b[2*l]);
    float y1 = dn * gelu_f(d1*rs*g[2*l+1] + b[2*l+1]);
    *(unsigned*)&hs[(size_t)node*128 + 2*l] = pk16(y0, y1);
  }
}

// ---------------- CSR gather over hs: 8 edge-slots per wave ----------------
__global__ __launch_bounds__(256) void k_gather(const _Float16* __restrict__ hs,
    const int* __restrict__ eSrc, const int* __restrict__ row_start,
    const int* __restrict__ incount, const float* __restrict__ dinv,
    _Float16* __restrict__ aggh, int N)
{
  int w = threadIdx.x >> 6, l = threadIdx.x & 63;
  int node = (blockIdx.x << 2) + w;
  int g  = l >> 3;     // edge slot 0..7
  int li = l & 7;      // 32B chunk: cols li*16 .. li*16+15
  float dn = dinv[node];
  int start = row_start[node], cnt = incount[node];
  float acc[16];
  #pragma unroll
  for (int i = 0; i < 16; i++) acc[i] = 0.f;
  // virtual edge 0 = self-loop (hs already carries dinv_src scaling)
  for (int e = g; e < cnt + 1; e += 8){
    int s = (e == 0) ? node : eSrc[start + e - 1];
    const uint4* hp = (const uint4*)&hs[(size_t)s*128 + (li << 4)];
    uint4 v0 = hp[0], v1 = hp[1];
    half2v p0 = __builtin_bit_cast(half2v, v0.x), p1 = __builtin_bit_cast(half2v, v0.y);
    half2v p2 = __builtin_bit_cast(half2v, v0.z), p3 = __builtin_bit_cast(half2v, v0.w);
    half2v p4 = __builtin_bit_cast(half2v, v1.x), p5 = __builtin_bit_cast(half2v, v1.y);
    half2v p6 = __builtin_bit_cast(half2v, v1.z), p7 = __builtin_bit_cast(half2v, v1.w);
    acc[0]  += (float)p0.x; acc[1]  += (float)p0.y;
    acc[2]  += (float)p1.x; acc[3]  += (float)p1.y;
    acc[4]  += (float)p2.x; acc[5]  += (float)p2.y;
    acc[6]  += (float)p3.x; acc[7]  += (float)p3.y;
    acc[8]  += (float)p4.x; acc[9]  += (float)p4.y;
    acc[10] += (float)p5.x; acc[11] += (float)p5.y;
    acc[12] += (float)p6.x; acc[13] += (float)p6.y;
    acc[14] += (float)p7.x; acc[15] += (float)p7.y;
  }
  #pragma unroll
  for (int i = 0; i < 16; i++){
    acc[i] += __shfl_xor(acc[i], 8);
    acc[i] += __shfl_xor(acc[i], 16);
    acc[i] += __shfl_xor(acc[i], 32);
  }
  if (l < 8){
    uint4 o0, o1;
    o0.x = pk16(dn*acc[0],  dn*acc[1]);  o0.y = pk16(dn*acc[2],  dn*acc[3]);
    o0.z = pk16(dn*acc[4],  dn*acc[5]);  o0.w = pk16(dn*acc[6],  dn*acc[7]);
    o1.x = pk16(dn*acc[8],  dn*acc[9]);  o1.y = pk16(dn*acc[10], dn*acc[11]);
    o1.z = pk16(dn*acc[12], dn*acc[13]); o1.w = pk16(dn*acc[14], dn*acc[15]);
    uint4* op = (uint4*)&aggh[(size_t)node*128 + (l << 4)];
    op[0] = o0; op[1] = o1;
  }
}

// ---------------- fused conv-GEMM + LN2 + FFN ----------------
// LDS map (shorts):
//   S_x  [0,    4352): 32 rows x stride 136 — conv out f16, then LN2 out f16
//   S_dyn[4352, 8704): phase A0/A: aggh staging (stride 136, 32 rows)
//                      FFN halves: S_t = 16 rows x stride 264 (one 256-col pass)
// Total 17408 B. launch_bounds(256,6): VGPR cap ~85 (no spill; round-10's
// (256,8) forced VGPR=32 -> 1.8 GB scratch traffic, 650us).
__global__ __launch_bounds__(256, 6) void k_ffn(
    const float* __restrict__ nf, const _Float16* __restrict__ aggh,
    const _Float16* __restrict__ Wcp, const float* __restrict__ bc,
    const float* __restrict__ g2, const float* __restrict__ bl2,
    const _Float16* __restrict__ W1p, const float* __restrict__ b1,
    const _Float16* __restrict__ W2p, const float* __restrict__ b2,
    float* __restrict__ out, int N)
{
  __shared__ __align__(16) unsigned short u_s[8704];
  int t = threadIdx.x, w = t >> 6, l = t & 63;
  int nb = blockIdx.x << 5;
  int quad = l >> 4, ln16 = l & 15;

  // ---- A0: stage aggh coalesced -> S_dyn (stride 136)
  {
    int m = t >> 3, c0 = (t & 7) << 4;
    const uint4* src = (const uint4*)&aggh[(size_t)(nb + m)*128 + c0];
    uint4 v0 = src[0], v1 = src[1];
    uint4* dst = (uint4*)&u_s[4352 + m*136 + c0];
    dst[0] = v0; dst[1] = v1;
  }
  __syncthreads();

  // ---- A: conv MFMA; write (aggW + bc) f16 -> S_x
  {
    const half8* Wp8 = (const half8*)Wcp;
    #pragma unroll
    for (int nt = 0; nt < 2; nt++){
      int tile = (w << 1) + nt;
      half8 bf[4];
      #pragma unroll
      for (int kb = 0; kb < 4; kb++) bf[kb] = Wp8[(size_t)((tile << 2) + kb)*64 + l];
      int col = (tile << 4) + ln16;
      float bcv = bc[col];
      #pragma unroll
      for (int mt = 0; mt < 2; mt++){
        floatx4 acc = {0.f,0.f,0.f,0.f};
        #pragma unroll
        for (int kb = 0; kb < 4; kb++){
          half8 ag = *(const half8*)&u_s[4352 + ((mt << 4) + ln16)*136 + (kb << 5) + (quad << 3)];
          acc = __builtin_amdgcn_mfma_f32_16x16x32_f16(ag, bf[kb], acc, 0, 0, 0);
        }
        #pragma unroll
        for (int r = 0; r < 4; r++)
          *(_Float16*)&u_s[((mt << 4) + (quad << 2) + r)*136 + col] = (_Float16)(acc[r] + bcv);
      }
    }
  }
  __syncthreads();

  // ---- B: LN2 on (S_x + nf) in place, coalesced
  {
    float ga = g2[2*l], gb = g2[2*l+1], ba = bl2[2*l], bb = bl2[2*l+1];
    #pragma unroll
    for (int q = 0; q < 8; q++){
      int m = (w << 3) + q;
      unsigned pu = *(unsigned*)&u_s[m*136 + 2*l];
      half2v hp = __builtin_bit_cast(half2v, pu);
      float2 nv = *(const float2*)&nf[(size_t)(nb + m)*128 + 2*l];
      float x0 = (float)hp.x + nv.x;
      float x1 = (float)hp.y + nv.y;
      float mu = wave_reduce_sum(x0 + x1) * 0.0078125f;
      float d0 = x0 - mu, d1 = x1 - mu;
      float var = wave_reduce_sum(d0*d0 + d1*d1) * 0.0078125f;
      float rs = rsqrtf(var + 1e-5f);
      float y0 = d0*rs*ga + ba;
      float y1 = d1*rs*gb + bb;
      *(unsigned*)&u_s[m*136 + 2*l] = pk16(y0, y1);
    }
  }
  __syncthreads();

  // ---- FFN: two 16-row halves; per half two 256-col passes of t with
  //      immediate partial stage-2 accumulation.
  const half8* W1p8 = (const half8*)W1p;
  const half8* W2p8 = (const half8*)W2p;
  int tile0 = (w << 1), tile1 = tile0 + 1;
  int col0 = (tile0 << 4) + ln16, col1 = (tile1 << 4) + ln16;
  float bv20 = b2[col0], bv21 = b2[col1];

  for (int h = 0; h < 2; h++){
    half8 ah[4];
    #pragma unroll
    for (int kb = 0; kb < 4; kb++)
      ah[kb] = *(const half8*)&u_s[((h << 4) + ln16)*136 + (kb << 5) + (quad << 3)];
    floatx4 acc0 = {0.f,0.f,0.f,0.f}, acc1 = {0.f,0.f,0.f,0.f};
    for (int p = 0; p < 2; p++){
      // stage 1: this pass's 16 N-tiles (cols [256p, 256p+256)), 4 per wave
      #pragma unroll
      for (int nt = 0; nt < 4; nt++){
        int tile = (p << 4) + (w << 2) + nt;
        half8 bf[4];
        #pragma unroll
        for (int kb = 0; kb < 4; kb++) bf[kb] = W1p8[(size_t)((tile << 2) + kb)*64 + l];
        floatx4 acc = {0.f,0.f,0.f,0.f};
        #pragma unroll
        for (int kb = 0; kb < 4; kb++)
          acc = __builtin_amdgcn_mfma_f32_16x16x32_f16(ah[kb], bf[kb], acc, 0, 0, 0);
        int colg = (tile << 4) + ln16;
        int lcol = colg - (p << 8);
        float bv = b1[colg];
        #pragma unroll
        for (int r = 0; r < 4; r++)
          *(_Float16*)&u_s[4352 + ((quad << 2) + r)*264 + lcol] = (_Float16)gelu_f(acc[r] + bv);
      }
      __syncthreads();
      // stage 2 partial: K range [256p, 256p+256)
      #pragma unroll
      for (int kbl = 0; kbl < 8; kbl++){
        half8 a0 = *(const half8*)&u_s[4352 + ln16*264 + (kbl << 5) + (quad << 3)];
        int kbg = (p << 3) + kbl;
        half8 b0  = W2p8[(size_t)((tile0 << 4) + kbg)*64 + l];
        half8 b1v = W2p8[(size_t)((tile1 << 4) + kbg)*64 + l];
        acc0 = __builtin_amdgcn_mfma_f32_16x16x32_f16(a0, b0,  acc0, 0, 0, 0);
        acc1 = __builtin_amdgcn_mfma_f32_16x16x32_f16(a0, b1v, acc1, 0, 0, 0);
      }
      __syncthreads();
    }
    // D-layout epilogue: out = nf + gelu(acc + b2)  (rows 16h + 4*quad + r)
    #pragma unroll
    for (int r = 0; r < 4; r++){
      int m = (h << 4) + (quad << 2) + r;
      size_t base = (size_t)(nb + m)*128;
      out[base + col0] = nf[base + col0] + gelu_f(acc0[r] + bv20);
      out[base + col1] = nf[base + col1] + gelu_f(acc1[r] + bv21);
    }
  }
}

extern "C" void kernel_launch(void* const* d_in, const int* in_sizes, int n_in,
                              void* d_out, int out_size, void* d_ws, size_t ws_size,
                              hipStream_t stream) {
  const float* nf   = (const float*)d_in[0];
  const int*   ei   = (const int*)  d_in[1];
  const float* ln1g = (const float*)d_in[3];
  const float* ln1b = (const float*)d_in[4];
  const float* Wc   = (const float*)d_in[5];
  const float* bc   = (const float*)d_in[6];
  const float* ln2g = (const float*)d_in[7];
  const float* ln2b = (const float*)d_in[8];
  const float* W1   = (const float*)d_in[9];
  const float* b1   = (const float*)d_in[10];
  const float* W2   = (const float*)d_in[11];
  const float* b2   = (const float*)d_in[12];
  float* out = (float*)d_out;

  int N = in_sizes[0] / 128;
  int E = in_sizes[1] / 2;
  int NB  = (N + 63) >> 6;            // 1563
  int ESB = (E + SBLK - 1) / SBLK;    // 7813

  char* ws = (char*)d_ws;
  _Float16* hs   = (_Float16*)ws;                              // [N,128] f16
  _Float16* aggh = (_Float16*)(ws + (size_t)N*128*2);          // [N,128] f16
  char* p = ws + (size_t)N*128*4;
  p = (char*)(((size_t)p + 15) & ~(size_t)15);
  int*   cnt         = (int*)p;   p += (size_t)SBLK*NB*4;
  int*   total       = (int*)p;   p += (size_t)NB*4;
  int*   bucketStart = (int*)p;   p += (size_t)(NB+1)*4;
  float* dinv        = (float*)p; p += (size_t)N*4;
  int*   incount     = (int*)p;   p += (size_t)N*4;
  int*   row_start   = (int*)p;   p += (size_t)N*4;
  int*   eb          = (int*)p;   p += (size_t)E*4;
  int*   eSrc        = (int*)p;   p += (size_t)E*4;
  p = (char*)(((size_t)p + 15) & ~(size_t)15);
  _Float16* Wcp = (_Float16*)p; p += (size_t)2048*8*2;    // 32 KB
  _Float16* W1p = (_Float16*)p; p += (size_t)8192*8*2;    // 128 KB
  _Float16* W2p = (_Float16*)p; p += (size_t)8192*8*2;    // 128 KB

  k_hist   <<<SBLK, 256, 0, stream>>>(ei, cnt, E, NB, ESB);
  k_scanB  <<<NB, 128, 0, stream>>>(cnt, total, NB);
  k_scan2  <<<1, 256, 0, stream>>>(total, bucketStart, NB);
  k_scatter<<<SBLK, 256, 0, stream>>>(ei, cnt, bucketStart, eb, E, NB, ESB);
  k_sort2  <<<NB, 256, 0, stream>>>(eb, bucketStart, eSrc, row_start, incount, dinv, N);

  k_prep   <<<72 + N/4, 256, 0, stream>>>(Wc, W1, W2, Wcp, W1p, W2p, nf, ln1g, ln1b, dinv, hs);
  k_gather <<<N/4, 256, 0, stream>>>(hs, eSrc, row_start, incount, dinv, aggh, N);
  k_ffn    <<<N/32, 256, 0, stream>>>(nf, aggh, Wcp, bc, ln2g, ln2b, W1p, b1, W2p, b2, out, N);
}

// Round 3
// 304.666 us; speedup vs baseline: 2.9113x; 2.9113x over previous
//
#include <hip/hip_runtime.h>
#include <math.h>

// DeepGCN layer, round 12: occupancy via NATURAL register pressure.
//   r10/r11 post-mortem: any __launch_bounds__ min-waves arg makes the
//   allocator emit VGPR=32/40 (half the nominal cap -> unified-file AGPR
//   split) and spill ~1.8 GB scratch. Fix: no min-waves bound; instead
//   reduce liveness structurally so natural alloc lands <=64 (m69 step):
//     - ah[4] loaded per p-pass (dead in stage 2)
//     - no nfr[] register file (nf re-read in epilogue, L2-hot)
//     - unroll 1 on nt/q/h/p loops, unroll 2 on stage-2 kbl loop
//     - epilogue recomputes cols/biases
//   LDS stays 17408 B (9 blocks/CU); VGPR<=64 -> 8 blocks/CU.
// MFMA 16x16x32 f16 layouts (m89/m101):
//   A[m = lane&15][k = (lane>>4)*8 + j]   (half8)
//   B[k = (lane>>4)*8 + j][n = lane&15]
//   D[m = (lane>>4)*4 + r][n = lane&15]   (float4)
// N = 100000 (multiple of 32), E = 1000000. NB <= 2048.

typedef _Float16 half8  __attribute__((ext_vector_type(8)));
typedef _Float16 half2v __attribute__((ext_vector_type(2)));
typedef __fp16   fp16x2 __attribute__((ext_vector_type(2)));
typedef float    floatx4 __attribute__((ext_vector_type(4)));

#define SBLK 128   // hist/scatter edge-chunks

__device__ __forceinline__ float gelu_f(float x){
  float x2 = x*x;
  float z  = x*(1.5957691216f + 0.07135481283f*x2);
  float e  = __expf(-z);
  return x * __builtin_amdgcn_rcpf(1.0f + e);
}
__device__ __forceinline__ unsigned pk16(float a, float b){
  fp16x2 h = __builtin_amdgcn_cvt_pkrtz(a, b);
  return __builtin_bit_cast(unsigned, h);
}
__device__ __forceinline__ float wave_reduce_sum(float v){
  #pragma unroll
  for (int off = 32; off > 0; off >>= 1) v += __shfl_xor(v, off, 64);
  return v;
}

// ---------------- two-level counting sort ----------------
__global__ __launch_bounds__(256) void k_hist(const int* __restrict__ ei, int* __restrict__ cnt,
                                              int E, int NB, int ESB){
  __shared__ int h[2048];
  int t = threadIdx.x;
  for (int i = t; i < NB; i += 256) h[i] = 0;
  __syncthreads();
  int e0 = blockIdx.x * ESB;
  int e1 = min(E, e0 + ESB);
  for (int e = e0 + t; e < e1; e += 256)
    atomicAdd(&h[ei[E + e] >> 6], 1);
  __syncthreads();
  for (int i = t; i < NB; i += 256) cnt[(size_t)blockIdx.x * NB + i] = h[i];
}

// block b: exclusive scan of cnt[0..SBLK)[b]; total -> total[b]
__global__ __launch_bounds__(128) void k_scanB(int* __restrict__ cnt, int* __restrict__ total,
                                               int NB){
  __shared__ int w0sum;
  int b = blockIdx.x;
  int t = threadIdx.x, l = t & 63, w = t >> 6;
  int v = cnt[(size_t)t*NB + b];
  int x = v;
  #pragma unroll
  for (int off = 1; off < 64; off <<= 1){
    int y = __shfl_up(x, off);
    if (l >= off) x += y;
  }
  if (w == 0 && l == 63) w0sum = x;
  __syncthreads();
  int ex = x - v + (w ? w0sum : 0);
  cnt[(size_t)t*NB + b] = ex;
  if (t == 127) total[b] = ex + v;
}

// single-block scan of totals -> bucketStart[NB+1]
__global__ __launch_bounds__(256) void k_scan2(const int* __restrict__ total,
                                               int* __restrict__ bucketStart, int NB){
  __shared__ int wsum[4];
  int t = threadIdx.x, w = t >> 6, l = t & 63;
  int vals[8];
  int sum = 0;
  #pragma unroll
  for (int j = 0; j < 8; j++){
    int idx = t*8 + j;
    vals[j] = (idx < NB) ? total[idx] : 0;
    sum += vals[j];
  }
  int x = sum;
  #pragma unroll
  for (int off = 1; off < 64; off <<= 1){
    int y = __shfl_up(x, off);
    if (l >= off) x += y;
  }
  if (l == 63) wsum[w] = x;
  __syncthreads();
  if (t == 0){
    int s = 0;
    #pragma unroll
    for (int i = 0; i < 4; i++){ int c = wsum[i]; wsum[i] = s; s += c; }
  }
  __syncthreads();
  int run = wsum[w] + x - sum;
  #pragma unroll
  for (int j = 0; j < 8; j++){
    int idx = t*8 + j;
    if (idx < NB) bucketStart[idx] = run;
    run += vals[j];
  }
  if (t == 255) bucketStart[NB] = run;   // == E
}

__global__ __launch_bounds__(256) void k_scatter(const int* __restrict__ ei,
    const int* __restrict__ cnt, const int* __restrict__ bucketStart,
    int* __restrict__ eb, int E, int NB, int ESB){
  __shared__ int cur[2048];
  int t = threadIdx.x;
  for (int i = t; i < NB; i += 256)
    cur[i] = bucketStart[i] + cnt[(size_t)blockIdx.x*NB + i];
  __syncthreads();
  int e0 = blockIdx.x*ESB, e1 = min(E, e0 + ESB);
  for (int e = e0 + t; e < e1; e += 256){
    int s = ei[e], d = ei[E + e];
    int pos = atomicAdd(&cur[d >> 6], 1);
    eb[pos] = (s << 6) | (d & 63);
  }
}

// per-bucket: sort by dst&63 -> eSrc; row_start/incount/dinv
__global__ __launch_bounds__(256) void k_sort2(const int* __restrict__ eb,
    const int* __restrict__ bucketStart, int* __restrict__ eSrc,
    int* __restrict__ row_start, int* __restrict__ incount,
    float* __restrict__ dinv, int N){
  __shared__ int hcnt[64];
  __shared__ int hcur[64];
  int b = blockIdx.x, t = threadIdx.x;
  if (t < 64) hcnt[t] = 0;
  __syncthreads();
  int s0 = bucketStart[b], s1 = bucketStart[b+1];
  for (int e = s0 + t; e < s1; e += 256) atomicAdd(&hcnt[eb[e] & 63], 1);
  __syncthreads();
  if (t < 64){
    int v = hcnt[t];
    int x = v;
    #pragma unroll
    for (int off = 1; off < 64; off <<= 1){
      int y = __shfl_up(x, off);
      if (t >= off) x += y;
    }
    int ex = x - v;
    hcur[t] = ex;
    int node = (b << 6) + t;
    if (node < N){
      row_start[node] = s0 + ex;
      incount[node]   = v;
      dinv[node]      = rsqrtf((float)v + 1.0f);
    }
  }
  __syncthreads();
  for (int e = s0 + t; e < s1; e += 256){
    int v = eb[e];
    int pos = atomicAdd(&hcur[v & 63], 1);
    eSrc[s0 + pos] = v >> 6;
  }
}

// ---------------- k_prep: weight pack (blocks 0..71) + scaled LN1/gelu ----------------
__global__ __launch_bounds__(256) void k_prep(
    const float* __restrict__ Wc, const float* __restrict__ W1, const float* __restrict__ W2,
    _Float16* __restrict__ Wcp, _Float16* __restrict__ W1p, _Float16* __restrict__ W2p,
    const float* __restrict__ nf, const float* __restrict__ g, const float* __restrict__ b,
    const float* __restrict__ dinv, _Float16* __restrict__ hs)
{
  int bid = blockIdx.x;
  if (bid < 72){
    int id = bid*256 + threadIdx.x;   // 18432 total
    const float* W; _Float16* P; int K, Nc, base;
    if (id < 2048)            { W = Wc; P = Wcp; K = 128; Nc = 128; base = id; }
    else if (id < 2048+8192)  { W = W1; P = W1p; K = 128; Nc = 512; base = id - 2048; }
    else                      { W = W2; P = W2p; K = 512; Nc = 128; base = id - 10240; }
    int lane = base & 63;
    int nkb  = K >> 5;
    int kb   = (base >> 6) % nkb;
    int tile = base / (nkb << 6);
    int col  = (tile << 4) + (lane & 15);
    int k0   = (kb << 5) + ((lane >> 4) << 3);
    _Float16 v[8];
    #pragma unroll
    for (int j = 0; j < 8; j++) v[j] = (_Float16)W[(size_t)(k0 + j)*Nc + col];
    *(half8*)&P[(size_t)base * 8] = *(const half8*)v;
  } else {
    int w = threadIdx.x >> 6, l = threadIdx.x & 63;
    int node = (bid - 72)*4 + w;
    float2 x = *(const float2*)&nf[(size_t)node*128 + 2*l];
    float mu = wave_reduce_sum(x.x + x.y) * 0.0078125f;
    float d0 = x.x - mu, d1 = x.y - mu;
    float var = wave_reduce_sum(d0*d0 + d1*d1) * 0.0078125f;
    float rs = rsqrtf(var + 1e-5f);
    float dn = dinv[node];
    float y0 = dn * gelu_f(d0*rs*g[2*l]   + b[2*l]);
    float y1 = dn * gelu_f(d1*rs*g[2*l+1] + b[2*l+1]);
    *(unsigned*)&hs[(size_t)node*128 + 2*l] = pk16(y0, y1);
  }
}

// ---------------- CSR gather over hs: 8 edge-slots per wave ----------------
__global__ __launch_bounds__(256) void k_gather(const _Float16* __restrict__ hs,
    const int* __restrict__ eSrc, const int* __restrict__ row_start,
    const int* __restrict__ incount, const float* __restrict__ dinv,
    _Float16* __restrict__ aggh, int N)
{
  int w = threadIdx.x >> 6, l = threadIdx.x & 63;
  int node = (blockIdx.x << 2) + w;
  int g  = l >> 3;     // edge slot 0..7
  int li = l & 7;      // 32B chunk: cols li*16 .. li*16+15
  float dn = dinv[node];
  int start = row_start[node], cnt = incount[node];
  float acc[16];
  #pragma unroll
  for (int i = 0; i < 16; i++) acc[i] = 0.f;
  // virtual edge 0 = self-loop (hs already carries dinv_src scaling)
  for (int e = g; e < cnt + 1; e += 8){
    int s = (e == 0) ? node : eSrc[start + e - 1];
    const uint4* hp = (const uint4*)&hs[(size_t)s*128 + (li << 4)];
    uint4 v0 = hp[0], v1 = hp[1];
    half2v p0 = __builtin_bit_cast(half2v, v0.x), p1 = __builtin_bit_cast(half2v, v0.y);
    half2v p2 = __builtin_bit_cast(half2v, v0.z), p3 = __builtin_bit_cast(half2v, v0.w);
    half2v p4 = __builtin_bit_cast(half2v, v1.x), p5 = __builtin_bit_cast(half2v, v1.y);
    half2v p6 = __builtin_bit_cast(half2v, v1.z), p7 = __builtin_bit_cast(half2v, v1.w);
    acc[0]  += (float)p0.x; acc[1]  += (float)p0.y;
    acc[2]  += (float)p1.x; acc[3]  += (float)p1.y;
    acc[4]  += (float)p2.x; acc[5]  += (float)p2.y;
    acc[6]  += (float)p3.x; acc[7]  += (float)p3.y;
    acc[8]  += (float)p4.x; acc[9]  += (float)p4.y;
    acc[10] += (float)p5.x; acc[11] += (float)p5.y;
    acc[12] += (float)p6.x; acc[13] += (float)p6.y;
    acc[14] += (float)p7.x; acc[15] += (float)p7.y;
  }
  #pragma unroll
  for (int i = 0; i < 16; i++){
    acc[i] += __shfl_xor(acc[i], 8);
    acc[i] += __shfl_xor(acc[i], 16);
    acc[i] += __shfl_xor(acc[i], 32);
  }
  if (l < 8){
    uint4 o0, o1;
    o0.x = pk16(dn*acc[0],  dn*acc[1]);  o0.y = pk16(dn*acc[2],  dn*acc[3]);
    o0.z = pk16(dn*acc[4],  dn*acc[5]);  o0.w = pk16(dn*acc[6],  dn*acc[7]);
    o1.x = pk16(dn*acc[8],  dn*acc[9]);  o1.y = pk16(dn*acc[10], dn*acc[11]);
    o1.z = pk16(dn*acc[12], dn*acc[13]); o1.w = pk16(dn*acc[14], dn*acc[15]);
    uint4* op = (uint4*)&aggh[(size_t)node*128 + (l << 4)];
    op[0] = o0; op[1] = o1;
  }
}

// ---------------- fused conv-GEMM + LN2 + FFN ----------------
// LDS map (shorts):
//   S_x  [0,    4352): 32 rows x stride 136 — conv out f16, then LN2 out f16
//   S_dyn[4352, 8704): phase A0/A: aggh staging (stride 136, 32 rows)
//                      FFN: t buffer, 16 rows x stride 264 (one 256-col pass)
// Total 17408 B. NO min-waves bound (r10/r11: it forces VGPR 32/40 + 1.8 GB
// scratch). Liveness shaped for natural <=64 VGPR -> 8 blocks/CU.
__global__ __launch_bounds__(256) void k_ffn(
    const float* __restrict__ nf, const _Float16* __restrict__ aggh,
    const _Float16* __restrict__ Wcp, const float* __restrict__ bc,
    const float* __restrict__ g2, const float* __restrict__ bl2,
    const _Float16* __restrict__ W1p, const float* __restrict__ b1,
    const _Float16* __restrict__ W2p, const float* __restrict__ b2,
    float* __restrict__ out, int N)
{
  __shared__ __align__(16) unsigned short u_s[8704];
  int t = threadIdx.x, w = t >> 6, l = t & 63;
  int nb = blockIdx.x << 5;
  int quad = l >> 4, ln16 = l & 15;

  // ---- A0: stage aggh coalesced -> S_dyn (stride 136)
  {
    int m = t >> 3, c0 = (t & 7) << 4;
    const uint4* src = (const uint4*)&aggh[(size_t)(nb + m)*128 + c0];
    uint4 v0 = src[0], v1 = src[1];
    uint4* dst = (uint4*)&u_s[4352 + m*136 + c0];
    dst[0] = v0; dst[1] = v1;
  }
  __syncthreads();

  // ---- A: conv MFMA; write (aggW + bc) f16 -> S_x
  {
    const half8* Wp8 = (const half8*)Wcp;
    #pragma unroll 1
    for (int nt = 0; nt < 2; nt++){
      int tile = (w << 1) + nt;
      half8 bf[4];
      #pragma unroll
      for (int kb = 0; kb < 4; kb++) bf[kb] = Wp8[(size_t)((tile << 2) + kb)*64 + l];
      int col = (tile << 4) + ln16;
      float bcv = bc[col];
      #pragma unroll
      for (int mt = 0; mt < 2; mt++){
        floatx4 acc = {0.f,0.f,0.f,0.f};
        #pragma unroll
        for (int kb = 0; kb < 4; kb++){
          half8 ag = *(const half8*)&u_s[4352 + ((mt << 4) + ln16)*136 + (kb << 5) + (quad << 3)];
          acc = __builtin_amdgcn_mfma_f32_16x16x32_f16(ag, bf[kb], acc, 0, 0, 0);
        }
        #pragma unroll
        for (int r = 0; r < 4; r++)
          *(_Float16*)&u_s[((mt << 4) + (quad << 2) + r)*136 + col] = (_Float16)(acc[r] + bcv);
      }
    }
  }
  __syncthreads();

  // ---- B: LN2 on (S_x + nf) in place, coalesced
  {
    float ga = g2[2*l], gb = g2[2*l+1], ba = bl2[2*l], bb = bl2[2*l+1];
    #pragma unroll 1
    for (int q = 0; q < 8; q++){
      int m = (w << 3) + q;
      unsigned pu = *(unsigned*)&u_s[m*136 + 2*l];
      half2v hp = __builtin_bit_cast(half2v, pu);
      float2 nv = *(const float2*)&nf[(size_t)(nb + m)*128 + 2*l];
      float x0 = (float)hp.x + nv.x;
      float x1 = (float)hp.y + nv.y;
      float mu = wave_reduce_sum(x0 + x1) * 0.0078125f;
      float d0 = x0 - mu, d1 = x1 - mu;
      float var = wave_reduce_sum(d0*d0 + d1*d1) * 0.0078125f;
      float rs = rsqrtf(var + 1e-5f);
      float y0 = d0*rs*ga + ba;
      float y1 = d1*rs*gb + bb;
      *(unsigned*)&u_s[m*136 + 2*l] = pk16(y0, y1);
    }
  }
  __syncthreads();

  // ---- FFN: two 16-row halves; per half two 256-col passes of t with
  //      immediate partial stage-2 accumulation. ah reloaded per pass so it
  //      is dead during stage 2 (liveness control).
  const half8* W1p8 = (const half8*)W1p;
  const half8* W2p8 = (const half8*)W2p;

  #pragma unroll 1
  for (int h = 0; h < 2; h++){
    floatx4 acc0 = {0.f,0.f,0.f,0.f}, acc1 = {0.f,0.f,0.f,0.f};
    #pragma unroll 1
    for (int p = 0; p < 2; p++){
      // stage 1: this pass's 16 N-tiles (cols [256p, 256p+256)), 4 per wave
      {
        half8 ah[4];
        #pragma unroll
        for (int kb = 0; kb < 4; kb++)
          ah[kb] = *(const half8*)&u_s[((h << 4) + ln16)*136 + (kb << 5) + (quad << 3)];
        #pragma unroll 1
        for (int nt = 0; nt < 4; nt++){
          int tile = (p << 4) + (w << 2) + nt;
          half8 bf[4];
          #pragma unroll
          for (int kb = 0; kb < 4; kb++) bf[kb] = W1p8[(size_t)((tile << 2) + kb)*64 + l];
          floatx4 acc = {0.f,0.f,0.f,0.f};
          #pragma unroll
          for (int kb = 0; kb < 4; kb++)
            acc = __builtin_amdgcn_mfma_f32_16x16x32_f16(ah[kb], bf[kb], acc, 0, 0, 0);
          int colg = (tile << 4) + ln16;
          float bv = b1[colg];
          int lcol = colg - (p << 8);
          #pragma unroll
          for (int r = 0; r < 4; r++)
            *(_Float16*)&u_s[4352 + ((quad << 2) + r)*264 + lcol] = (_Float16)gelu_f(acc[r] + bv);
        }
      }
      __syncthreads();
      // stage 2 partial: K range [256p, 256p+256)
      #pragma unroll 2
      for (int kbl = 0; kbl < 8; kbl++){
        half8 a0 = *(const half8*)&u_s[4352 + ln16*264 + (kbl << 5) + (quad << 3)];
        int kbg = (p << 3) + kbl;
        half8 b0  = W2p8[(size_t)(((w << 1) << 4) + kbg)*64 + l];
        half8 b1v = W2p8[(size_t)((((w << 1) + 1) << 4) + kbg)*64 + l];
        acc0 = __builtin_amdgcn_mfma_f32_16x16x32_f16(a0, b0,  acc0, 0, 0, 0);
        acc1 = __builtin_amdgcn_mfma_f32_16x16x32_f16(a0, b1v, acc1, 0, 0, 0);
      }
      __syncthreads();
    }
    // D-layout epilogue: out = nf + gelu(acc + b2)  (rows 16h + 4*quad + r)
    {
      int col0 = ((w << 1) << 4) + ln16, col1 = (((w << 1) + 1) << 4) + ln16;
      float bv20 = b2[col0], bv21 = b2[col1];
      #pragma unroll
      for (int r = 0; r < 4; r++){
        int m = (h << 4) + (quad << 2) + r;
        size_t base = (size_t)(nb + m)*128;
        out[base + col0] = nf[base + col0] + gelu_f(acc0[r] + bv20);
        out[base + col1] = nf[base + col1] + gelu_f(acc1[r] + bv21);
      }
    }
  }
}

extern "C" void kernel_launch(void* const* d_in, const int* in_sizes, int n_in,
                              void* d_out, int out_size, void* d_ws, size_t ws_size,
                              hipStream_t stream) {
  const float* nf   = (const float*)d_in[0];
  const int*   ei   = (const int*)  d_in[1];
  const float* ln1g = (const float*)d_in[3];
  const float* ln1b = (const float*)d_in[4];
  const float* Wc   = (const float*)d_in[5];
  const float* bc   = (const float*)d_in[6];
  const float* ln2g = (const float*)d_in[7];
  const float* ln2b = (const float*)d_in[8];
  const float* W1   = (const float*)d_in[9];
  const float* b1   = (const float*)d_in[10];
  const float* W2   = (const float*)d_in[11];
  const float* b2   = (const float*)d_in[12];
  float* out = (float*)d_out;

  int N = in_sizes[0] / 128;
  int E = in_sizes[1] / 2;
  int NB  = (N + 63) >> 6;            // 1563
  int ESB = (E + SBLK - 1) / SBLK;    // 7813

  char* ws = (char*)d_ws;
  _Float16* hs   = (_Float16*)ws;                              // [N,128] f16
  _Float16* aggh = (_Float16*)(ws + (size_t)N*128*2);          // [N,128] f16
  char* p = ws + (size_t)N*128*4;
  p = (char*)(((size_t)p + 15) & ~(size_t)15);
  int*   cnt         = (int*)p;   p += (size_t)SBLK*NB*4;
  int*   total       = (int*)p;   p += (size_t)NB*4;
  int*   bucketStart = (int*)p;   p += (size_t)(NB+1)*4;
  float* dinv        = (float*)p; p += (size_t)N*4;
  int*   incount     = (int*)p;   p += (size_t)N*4;
  int*   row_start   = (int*)p;   p += (size_t)N*4;
  int*   eb          = (int*)p;   p += (size_t)E*4;
  int*   eSrc        = (int*)p;   p += (size_t)E*4;
  p = (char*)(((size_t)p + 15) & ~(size_t)15);
  _Float16* Wcp = (_Float16*)p; p += (size_t)2048*8*2;    // 32 KB
  _Float16* W1p = (_Float16*)p; p += (size_t)8192*8*2;    // 128 KB
  _Float16* W2p = (_Float16*)p; p += (size_t)8192*8*2;    // 128 KB

  k_hist   <<<SBLK, 256, 0, stream>>>(ei, cnt, E, NB, ESB);
  k_scanB  <<<NB, 128, 0, stream>>>(cnt, total, NB);
  k_scan2  <<<1, 256, 0, stream>>>(total, bucketStart, NB);
  k_scatter<<<SBLK, 256, 0, stream>>>(ei, cnt, bucketStart, eb, E, NB, ESB);
  k_sort2  <<<NB, 256, 0, stream>>>(eb, bucketStart, eSrc, row_start, incount, dinv, N);

  k_prep   <<<72 + N/4, 256, 0, stream>>>(Wc, W1, W2, Wcp, W1p, W2p, nf, ln1g, ln1b, dinv, hs);
  k_gather <<<N/4, 256, 0, stream>>>(hs, eSrc, row_start, incount, dinv, aggh, N);
  k_ffn    <<<N/32, 256, 0, stream>>>(nf, aggh, Wcp, bc, ln2g, ln2b, W1p, b1, W2p, b2, out, N);
}

// Round 4
// 286.779 us; speedup vs baseline: 3.0929x; 1.0624x over previous
//
#include <hip/hip_runtime.h>
#include <math.h>

// DeepGCN layer, round 13: revert k_ffn to round-0 (75us known-good) + kill
// the k_prep serial dispatch.
//   r12 post-mortem: occupancy 27->69% made k_ffn SLOWER (99us) — not
//   latency-bound; the extra barriers + unroll-1 ILP loss dominated. k_ffn
//   reverted verbatim (VGPR 72, LDS 33280, 4 blk/CU).
//   New: dinv[src] applied per-edge in k_gather (fma replaces add), so LN1/hs
//   no longer depends on the sort pipeline -> LN1 + weight-pack fused into
//   k_hist's grid (hist atomics + LN1 VALU are resource-complementary);
//   k_prep launch removed.
// MFMA 16x16x32 f16 layouts (m89/m101):
//   A[m = lane&15][k = (lane>>4)*8 + j]   (half8)
//   B[k = (lane>>4)*8 + j][n = lane&15]
//   D[m = (lane>>4)*4 + r][n = lane&15]   (float4)
// N = 100000 (multiple of 32), E = 1000000. NB <= 2048.

typedef _Float16 half8  __attribute__((ext_vector_type(8)));
typedef _Float16 half2v __attribute__((ext_vector_type(2)));
typedef __fp16   fp16x2 __attribute__((ext_vector_type(2)));
typedef float    floatx4 __attribute__((ext_vector_type(4)));

#define SBLK 128   // hist/scatter edge-chunks

__device__ __forceinline__ float gelu_f(float x){
  float x2 = x*x;
  float z  = x*(1.5957691216f + 0.07135481283f*x2);
  float e  = __expf(-z);
  return x * __builtin_amdgcn_rcpf(1.0f + e);
}
__device__ __forceinline__ unsigned pk16(float a, float b){
  fp16x2 h = __builtin_amdgcn_cvt_pkrtz(a, b);
  return __builtin_bit_cast(unsigned, h);
}
__device__ __forceinline__ float wave_reduce_sum(float v){
  #pragma unroll
  for (int off = 32; off > 0; off >>= 1) v += __shfl_xor(v, off, 64);
  return v;
}

// ---------------- fused: hist chunks + weight pack + LN1/gelu (unscaled) ----
__global__ __launch_bounds__(256) void k_hist(const int* __restrict__ ei, int* __restrict__ cnt,
                                              int E, int NB, int ESB,
    const float* __restrict__ Wc, const float* __restrict__ W1, const float* __restrict__ W2,
    _Float16* __restrict__ Wcp, _Float16* __restrict__ W1p, _Float16* __restrict__ W2p,
    const float* __restrict__ nf, const float* __restrict__ g, const float* __restrict__ b,
    _Float16* __restrict__ hs)
{
  int bid = blockIdx.x;
  if (bid < SBLK){
    __shared__ int h[2048];
    int t = threadIdx.x;
    for (int i = t; i < NB; i += 256) h[i] = 0;
    __syncthreads();
    int e0 = bid * ESB;
    int e1 = min(E, e0 + ESB);
    for (int e = e0 + t; e < e1; e += 256)
      atomicAdd(&h[ei[E + e] >> 6], 1);
    __syncthreads();
    for (int i = t; i < NB; i += 256) cnt[(size_t)bid * NB + i] = h[i];
  } else if (bid < SBLK + 72){
    int id = (bid - SBLK)*256 + threadIdx.x;   // 18432 total
    const float* W; _Float16* P; int K, Nc, base;
    if (id < 2048)            { W = Wc; P = Wcp; K = 128; Nc = 128; base = id; }
    else if (id < 2048+8192)  { W = W1; P = W1p; K = 128; Nc = 512; base = id - 2048; }
    else                      { W = W2; P = W2p; K = 512; Nc = 128; base = id - 10240; }
    int lane = base & 63;
    int nkb  = K >> 5;
    int kb   = (base >> 6) % nkb;
    int tile = base / (nkb << 6);
    int col  = (tile << 4) + (lane & 15);
    int k0   = (kb << 5) + ((lane >> 4) << 3);
    _Float16 v[8];
    #pragma unroll
    for (int j = 0; j < 8; j++) v[j] = (_Float16)W[(size_t)(k0 + j)*Nc + col];
    *(half8*)&P[(size_t)base * 8] = *(const half8*)v;
  } else {
    int w = threadIdx.x >> 6, l = threadIdx.x & 63;
    int node = (bid - SBLK - 72)*4 + w;
    float2 x = *(const float2*)&nf[(size_t)node*128 + 2*l];
    float mu = wave_reduce_sum(x.x + x.y) * 0.0078125f;
    float d0 = x.x - mu, d1 = x.y - mu;
    float var = wave_reduce_sum(d0*d0 + d1*d1) * 0.0078125f;
    float rs = rsqrtf(var + 1e-5f);
    float y0 = gelu_f(d0*rs*g[2*l]   + b[2*l]);
    float y1 = gelu_f(d1*rs*g[2*l+1] + b[2*l+1]);
    *(unsigned*)&hs[(size_t)node*128 + 2*l] = pk16(y0, y1);
  }
}

// block b: exclusive scan of cnt[0..SBLK)[b]; total -> total[b]
__global__ __launch_bounds__(128) void k_scanB(int* __restrict__ cnt, int* __restrict__ total,
                                               int NB){
  __shared__ int w0sum;
  int b = blockIdx.x;
  int t = threadIdx.x, l = t & 63, w = t >> 6;
  int v = cnt[(size_t)t*NB + b];
  int x = v;
  #pragma unroll
  for (int off = 1; off < 64; off <<= 1){
    int y = __shfl_up(x, off);
    if (l >= off) x += y;
  }
  if (w == 0 && l == 63) w0sum = x;
  __syncthreads();
  int ex = x - v + (w ? w0sum : 0);
  cnt[(size_t)t*NB + b] = ex;
  if (t == 127) total[b] = ex + v;
}

// single-block scan of totals -> bucketStart[NB+1]
__global__ __launch_bounds__(256) void k_scan2(const int* __restrict__ total,
                                               int* __restrict__ bucketStart, int NB){
  __shared__ int wsum[4];
  int t = threadIdx.x, w = t >> 6, l = t & 63;
  int vals[8];
  int sum = 0;
  #pragma unroll
  for (int j = 0; j < 8; j++){
    int idx = t*8 + j;
    vals[j] = (idx < NB) ? total[idx] : 0;
    sum += vals[j];
  }
  int x = sum;
  #pragma unroll
  for (int off = 1; off < 64; off <<= 1){
    int y = __shfl_up(x, off);
    if (l >= off) x += y;
  }
  if (l == 63) wsum[w] = x;
  __syncthreads();
  if (t == 0){
    int s = 0;
    #pragma unroll
    for (int i = 0; i < 4; i++){ int c = wsum[i]; wsum[i] = s; s += c; }
  }
  __syncthreads();
  int run = wsum[w] + x - sum;
  #pragma unroll
  for (int j = 0; j < 8; j++){
    int idx = t*8 + j;
    if (idx < NB) bucketStart[idx] = run;
    run += vals[j];
  }
  if (t == 255) bucketStart[NB] = run;   // == E
}

__global__ __launch_bounds__(256) void k_scatter(const int* __restrict__ ei,
    const int* __restrict__ cnt, const int* __restrict__ bucketStart,
    int* __restrict__ eb, int E, int NB, int ESB){
  __shared__ int cur[2048];
  int t = threadIdx.x;
  for (int i = t; i < NB; i += 256)
    cur[i] = bucketStart[i] + cnt[(size_t)blockIdx.x*NB + i];
  __syncthreads();
  int e0 = blockIdx.x*ESB, e1 = min(E, e0 + ESB);
  for (int e = e0 + t; e < e1; e += 256){
    int s = ei[e], d = ei[E + e];
    int pos = atomicAdd(&cur[d >> 6], 1);
    eb[pos] = (s << 6) | (d & 63);
  }
}

// per-bucket: sort by dst&63 -> eSrc; row_start/incount/dinv
__global__ __launch_bounds__(256) void k_sort2(const int* __restrict__ eb,
    const int* __restrict__ bucketStart, int* __restrict__ eSrc,
    int* __restrict__ row_start, int* __restrict__ incount,
    float* __restrict__ dinv, int N){
  __shared__ int hcnt[64];
  __shared__ int hcur[64];
  int b = blockIdx.x, t = threadIdx.x;
  if (t < 64) hcnt[t] = 0;
  __syncthreads();
  int s0 = bucketStart[b], s1 = bucketStart[b+1];
  for (int e = s0 + t; e < s1; e += 256) atomicAdd(&hcnt[eb[e] & 63], 1);
  __syncthreads();
  if (t < 64){
    int v = hcnt[t];
    int x = v;
    #pragma unroll
    for (int off = 1; off < 64; off <<= 1){
      int y = __shfl_up(x, off);
      if (t >= off) x += y;
    }
    int ex = x - v;
    hcur[t] = ex;
    int node = (b << 6) + t;
    if (node < N){
      row_start[node] = s0 + ex;
      incount[node]   = v;
      dinv[node]      = rsqrtf((float)v + 1.0f);
    }
  }
  __syncthreads();
  for (int e = s0 + t; e < s1; e += 256){
    int v = eb[e];
    int pos = atomicAdd(&hcur[v & 63], 1);
    eSrc[s0 + pos] = v >> 6;
  }
}

// ---------------- CSR gather over hs: 8 edge-slots per wave ----------------
// hs is UNSCALED gelu(LN1(nf)); dinv[src] applied here via fma.
__global__ __launch_bounds__(256) void k_gather(const _Float16* __restrict__ hs,
    const int* __restrict__ eSrc, const int* __restrict__ row_start,
    const int* __restrict__ incount, const float* __restrict__ dinv,
    _Float16* __restrict__ aggh, int N)
{
  int w = threadIdx.x >> 6, l = threadIdx.x & 63;
  int node = (blockIdx.x << 2) + w;
  int g  = l >> 3;     // edge slot 0..7
  int li = l & 7;      // 32B chunk: cols li*16 .. li*16+15
  float dn = dinv[node];
  int start = row_start[node], cnt = incount[node];
  float acc[16];
  #pragma unroll
  for (int i = 0; i < 16; i++) acc[i] = 0.f;
  // virtual edge 0 = self-loop
  for (int e = g; e < cnt + 1; e += 8){
    int s = (e == 0) ? node : eSrc[start + e - 1];
    float ds = dinv[s];
    const uint4* hp = (const uint4*)&hs[(size_t)s*128 + (li << 4)];
    uint4 v0 = hp[0], v1 = hp[1];
    half2v p0 = __builtin_bit_cast(half2v, v0.x), p1 = __builtin_bit_cast(half2v, v0.y);
    half2v p2 = __builtin_bit_cast(half2v, v0.z), p3 = __builtin_bit_cast(half2v, v0.w);
    half2v p4 = __builtin_bit_cast(half2v, v1.x), p5 = __builtin_bit_cast(half2v, v1.y);
    half2v p6 = __builtin_bit_cast(half2v, v1.z), p7 = __builtin_bit_cast(half2v, v1.w);
    acc[0]  = fmaf((float)p0.x, ds, acc[0]);  acc[1]  = fmaf((float)p0.y, ds, acc[1]);
    acc[2]  = fmaf((float)p1.x, ds, acc[2]);  acc[3]  = fmaf((float)p1.y, ds, acc[3]);
    acc[4]  = fmaf((float)p2.x, ds, acc[4]);  acc[5]  = fmaf((float)p2.y, ds, acc[5]);
    acc[6]  = fmaf((float)p3.x, ds, acc[6]);  acc[7]  = fmaf((float)p3.y, ds, acc[7]);
    acc[8]  = fmaf((float)p4.x, ds, acc[8]);  acc[9]  = fmaf((float)p4.y, ds, acc[9]);
    acc[10] = fmaf((float)p5.x, ds, acc[10]); acc[11] = fmaf((float)p5.y, ds, acc[11]);
    acc[12] = fmaf((float)p6.x, ds, acc[12]); acc[13] = fmaf((float)p6.y, ds, acc[13]);
    acc[14] = fmaf((float)p7.x, ds, acc[14]); acc[15] = fmaf((float)p7.y, ds, acc[15]);
  }
  #pragma unroll
  for (int i = 0; i < 16; i++){
    acc[i] += __shfl_xor(acc[i], 8);
    acc[i] += __shfl_xor(acc[i], 16);
    acc[i] += __shfl_xor(acc[i], 32);
  }
  if (l < 8){
    uint4 o0, o1;
    o0.x = pk16(dn*acc[0],  dn*acc[1]);  o0.y = pk16(dn*acc[2],  dn*acc[3]);
    o0.z = pk16(dn*acc[4],  dn*acc[5]);  o0.w = pk16(dn*acc[6],  dn*acc[7]);
    o1.x = pk16(dn*acc[8],  dn*acc[9]);  o1.y = pk16(dn*acc[10], dn*acc[11]);
    o1.z = pk16(dn*acc[12], dn*acc[13]); o1.w = pk16(dn*acc[14], dn*acc[15]);
    uint4* op = (uint4*)&aggh[(size_t)node*128 + (l << 4)];
    op[0] = o0; op[1] = o1;
  }
}

// ---------------- fused conv-GEMM + LN2 + FFN, all coalesced (round-0) ------
__global__ __launch_bounds__(256) void k_ffn(
    const float* __restrict__ nf, const _Float16* __restrict__ aggh,
    const _Float16* __restrict__ Wcp, const float* __restrict__ bc,
    const float* __restrict__ g2, const float* __restrict__ bl2,
    const _Float16* __restrict__ W1p, const float* __restrict__ b1,
    const _Float16* __restrict__ W2p, const float* __restrict__ b2,
    float* __restrict__ out, int N)
{
  __shared__ __align__(16) unsigned short u_s[32*520];
  int t = threadIdx.x, w = t >> 6, l = t & 63;
  int nb = blockIdx.x << 5;
  int quad = l >> 4, ln16 = l & 15;

  // ---- A0: stage aggh coalesced -> LDS stride-136 region
  {
    int m = t >> 3, c0 = (t & 7) << 4;
    const uint4* src = (const uint4*)&aggh[(size_t)(nb + m)*128 + c0];
    uint4 v0 = src[0], v1 = src[1];
    uint4* dst = (uint4*)&u_s[4352 + m*136 + c0];
    dst[0] = v0; dst[1] = v1;
  }
  __syncthreads();

  // ---- A: conv MFMA; write (aggW + bc) f16 -> F16 region
  {
    half8 ag[2][4];
    #pragma unroll
    for (int mt = 0; mt < 2; mt++)
      #pragma unroll
      for (int kb = 0; kb < 4; kb++)
        ag[mt][kb] = *(const half8*)&u_s[4352 + ((mt << 4) + ln16)*136 + (kb << 5) + (quad << 3)];
    const half8* Wp8 = (const half8*)Wcp;
    #pragma unroll
    for (int nt = 0; nt < 2; nt++){
      int tile = (w << 1) + nt;
      half8 bf[4];
      #pragma unroll
      for (int kb = 0; kb < 4; kb++) bf[kb] = Wp8[(size_t)((tile << 2) + kb)*64 + l];
      floatx4 acc0 = {0.f,0.f,0.f,0.f}, acc1 = {0.f,0.f,0.f,0.f};
      #pragma unroll
      for (int kb = 0; kb < 4; kb++){
        acc0 = __builtin_amdgcn_mfma_f32_16x16x32_f16(ag[0][kb], bf[kb], acc0, 0, 0, 0);
        acc1 = __builtin_amdgcn_mfma_f32_16x16x32_f16(ag[1][kb], bf[kb], acc1, 0, 0, 0);
      }
      int col = (tile << 4) + ln16;
      float bcv = bc[col];
      #pragma unroll
      for (int r = 0; r < 4; r++){
        int m0 = (quad << 2) + r;
        *(_Float16*)&u_s[m0*136 + col]        = (_Float16)(acc0[r] + bcv);
        *(_Float16*)&u_s[(m0 + 16)*136 + col] = (_Float16)(acc1[r] + bcv);
      }
    }
  }
  __syncthreads();

  // ---- B: LN2 on (F16 + nf), coalesced; nf kept in registers
  float2 nfr[8];
  #pragma unroll
  for (int q = 0; q < 8; q++){
    int m = (w << 3) + q;
    unsigned pu = *(unsigned*)&u_s[m*136 + 2*l];
    half2v hp = __builtin_bit_cast(half2v, pu);
    nfr[q] = *(const float2*)&nf[(size_t)(nb + m)*128 + 2*l];
    float x0 = (float)hp.x + nfr[q].x;
    float x1 = (float)hp.y + nfr[q].y;
    float mu = wave_reduce_sum(x0 + x1) * 0.0078125f;
    float d0 = x0 - mu, d1 = x1 - mu;
    float var = wave_reduce_sum(d0*d0 + d1*d1) * 0.0078125f;
    float rs = rsqrtf(var + 1e-5f);
    float y0 = d0*rs*g2[2*l]   + bl2[2*l];
    float y1 = d1*rs*g2[2*l+1] + bl2[2*l+1];
    *(unsigned*)&u_s[m*136 + 2*l] = pk16(y0, y1);
  }
  __syncthreads();

  // A-fragments into registers; F16 region dead afterwards
  half8 a[2][4];
  #pragma unroll
  for (int mt = 0; mt < 2; mt++)
    #pragma unroll
    for (int kb = 0; kb < 4; kb++)
      a[mt][kb] = *(const half8*)&u_s[((mt << 4) + ln16)*136 + (kb << 5) + (quad << 3)];
  __syncthreads();

  // ---- stage 1: t = gelu(f @ W1 + b1) -> t_s (stride 520). Wave w: N-tiles [8w, 8w+8).
  {
    const half8* Wp8 = (const half8*)W1p;
    #pragma unroll
    for (int nt = 0; nt < 8; nt++){
      int tile = (w << 3) + nt;
      half8 bf[4];
      #pragma unroll
      for (int kb = 0; kb < 4; kb++) bf[kb] = Wp8[(size_t)((tile << 2) + kb)*64 + l];
      floatx4 acc0 = {0.f,0.f,0.f,0.f}, acc1 = {0.f,0.f,0.f,0.f};
      #pragma unroll
      for (int kb = 0; kb < 4; kb++){
        acc0 = __builtin_amdgcn_mfma_f32_16x16x32_f16(a[0][kb], bf[kb], acc0, 0, 0, 0);
        acc1 = __builtin_amdgcn_mfma_f32_16x16x32_f16(a[1][kb], bf[kb], acc1, 0, 0, 0);
      }
      int col = (tile << 4) + ln16;
      float bv = b1[col];
      #pragma unroll
      for (int r = 0; r < 4; r++){
        *(_Float16*)&u_s[((quad << 2) + r)*520 + col]      = (_Float16)gelu_f(acc0[r] + bv);
        *(_Float16*)&u_s[(16 + (quad << 2) + r)*520 + col] = (_Float16)gelu_f(acc1[r] + bv);
      }
    }
  }
  __syncthreads();

  // ---- stage 2: f2 = gelu(t @ W2 + b2). Wave w: N-tiles {2w, 2w+1}.
  floatx4 acc00 = {0.f,0.f,0.f,0.f}, acc01 = {0.f,0.f,0.f,0.f};
  floatx4 acc10 = {0.f,0.f,0.f,0.f}, acc11 = {0.f,0.f,0.f,0.f};
  int tile0 = (w << 1), tile1 = tile0 + 1;
  {
    const half8* Wp8 = (const half8*)W2p;
    for (int kb = 0; kb < 16; kb++){
      half8 a0 = *(const half8*)&u_s[ln16*520        + (kb << 5) + (quad << 3)];
      half8 a1 = *(const half8*)&u_s[(16 + ln16)*520 + (kb << 5) + (quad << 3)];
      half8 b0  = Wp8[(size_t)((tile0 << 4) + kb)*64 + l];
      half8 b1v = Wp8[(size_t)((tile1 << 4) + kb)*64 + l];
      acc00 = __builtin_amdgcn_mfma_f32_16x16x32_f16(a0, b0,  acc00, 0, 0, 0);
      acc01 = __builtin_amdgcn_mfma_f32_16x16x32_f16(a0, b1v, acc01, 0, 0, 0);
      acc10 = __builtin_amdgcn_mfma_f32_16x16x32_f16(a1, b0,  acc10, 0, 0, 0);
      acc11 = __builtin_amdgcn_mfma_f32_16x16x32_f16(a1, b1v, acc11, 0, 0, 0);
    }
  }
  __syncthreads();   // all t_s reads done; u_s reusable as fp32

  // ---- write f2 to LDS (fp32, stride 132), D-layout
  {
    float* fs = (float*)u_s;
    int col0 = (tile0 << 4) + ln16, col1 = (tile1 << 4) + ln16;
    float bv0 = b2[col0], bv1 = b2[col1];
    #pragma unroll
    for (int r = 0; r < 4; r++){
      int m0 = (quad << 2) + r;
      fs[m0*132 + col0]        = gelu_f(acc00[r] + bv0);
      fs[m0*132 + col1]        = gelu_f(acc01[r] + bv1);
      fs[(m0 + 16)*132 + col0] = gelu_f(acc10[r] + bv0);
      fs[(m0 + 16)*132 + col1] = gelu_f(acc11[r] + bv1);
    }
  }
  __syncthreads();

  // ---- coalesced residual epilogue: out = nf + f2
  {
    const float* fs = (const float*)u_s;
    #pragma unroll
    for (int q = 0; q < 8; q++){
      int m = (w << 3) + q;
      float2 o;
      o.x = nfr[q].x + fs[m*132 + 2*l];
      o.y = nfr[q].y + fs[m*132 + 2*l + 1];
      *(float2*)&out[(size_t)(nb + m)*128 + 2*l] = o;
    }
  }
}

extern "C" void kernel_launch(void* const* d_in, const int* in_sizes, int n_in,
                              void* d_out, int out_size, void* d_ws, size_t ws_size,
                              hipStream_t stream) {
  const float* nf   = (const float*)d_in[0];
  const int*   ei   = (const int*)  d_in[1];
  const float* ln1g = (const float*)d_in[3];
  const float* ln1b = (const float*)d_in[4];
  const float* Wc   = (const float*)d_in[5];
  const float* bc   = (const float*)d_in[6];
  const float* ln2g = (const float*)d_in[7];
  const float* ln2b = (const float*)d_in[8];
  const float* W1   = (const float*)d_in[9];
  const float* b1   = (const float*)d_in[10];
  const float* W2   = (const float*)d_in[11];
  const float* b2   = (const float*)d_in[12];
  float* out = (float*)d_out;

  int N = in_sizes[0] / 128;
  int E = in_sizes[1] / 2;
  int NB  = (N + 63) >> 6;            // 1563
  int ESB = (E + SBLK - 1) / SBLK;    // 7813

  char* ws = (char*)d_ws;
  _Float16* hs   = (_Float16*)ws;                              // [N,128] f16
  _Float16* aggh = (_Float16*)(ws + (size_t)N*128*2);          // [N,128] f16
  char* p = ws + (size_t)N*128*4;
  p = (char*)(((size_t)p + 15) & ~(size_t)15);
  int*   cnt         = (int*)p;   p += (size_t)SBLK*NB*4;
  int*   total       = (int*)p;   p += (size_t)NB*4;
  int*   bucketStart = (int*)p;   p += (size_t)(NB+1)*4;
  float* dinv        = (float*)p; p += (size_t)N*4;
  int*   incount     = (int*)p;   p += (size_t)N*4;
  int*   row_start   = (int*)p;   p += (size_t)N*4;
  int*   eb          = (int*)p;   p += (size_t)E*4;
  int*   eSrc        = (int*)p;   p += (size_t)E*4;
  p = (char*)(((size_t)p + 15) & ~(size_t)15);
  _Float16* Wcp = (_Float16*)p; p += (size_t)2048*8*2;    // 32 KB
  _Float16* W1p = (_Float16*)p; p += (size_t)8192*8*2;    // 128 KB
  _Float16* W2p = (_Float16*)p; p += (size_t)8192*8*2;    // 128 KB

  k_hist   <<<SBLK + 72 + N/4, 256, 0, stream>>>(ei, cnt, E, NB, ESB,
                                                 Wc, W1, W2, Wcp, W1p, W2p,
                                                 nf, ln1g, ln1b, hs);
  k_scanB  <<<NB, 128, 0, stream>>>(cnt, total, NB);
  k_scan2  <<<1, 256, 0, stream>>>(total, bucketStart, NB);
  k_scatter<<<SBLK, 256, 0, stream>>>(ei, cnt, bucketStart, eb, E, NB, ESB);
  k_sort2  <<<NB, 256, 0, stream>>>(eb, bucketStart, eSrc, row_start, incount, dinv, N);

  k_gather <<<N/4, 256, 0, stream>>>(hs, eSrc, row_start, incount, dinv, aggh, N);
  k_ffn    <<<N/32, 256, 0, stream>>>(nf, aggh, Wcp, bc, ln2g, ln2b, W1p, b1, W2p, b2, out, N);
}